// Round 1
// baseline (369.555 us; speedup 1.0000x reference)
//
#include <hip/hip_runtime.h>
#include <hip/hip_bf16.h>
#include <cstdint>

#define D_MODEL 256
#define NHEADS 8
#define DK 32
#define LDSPAD 8
#define LDSROW (D_MODEL + LDSPAD)   // 264 bf16 per LDS row
#define LDSROWF (D_MODEL + 4)       // 260 f32 per LDS row (gemm_out epilogue)
#define PBLK 170                    // persistent x-blocks (170*3=510 <= 512 = 2/CU)

typedef float f32x4 __attribute__((ext_vector_type(4)));
typedef __bf16 bf16x8 __attribute__((ext_vector_type(8)));
typedef unsigned short u16x8 __attribute__((ext_vector_type(8)));

__device__ __forceinline__ unsigned short f2bf_rne(float f) {
    unsigned int u = __float_as_uint(f);
    u += 0x7FFF + ((u >> 16) & 1);
    return (unsigned short)(u >> 16);
}
__device__ __forceinline__ float bf2f(unsigned short h) {
    return __uint_as_float(((unsigned int)h) << 16);
}

// ---------------- weight fp32 -> bf16 (MFMA B-fragment order) + edge histogram --
// Fused: first 32768 threads convert weights, remaining E threads do the dst
// histogram (independent work; saves one dispatch).
__global__ void conv_weights_hist(const float* __restrict__ W0, const float* __restrict__ W1,
                                  const float* __restrict__ W2, const float* __restrict__ W3,
                                  unsigned short* __restrict__ out,
                                  const int* __restrict__ dst, int E,
                                  int* __restrict__ counts) {
    int i = blockIdx.x * blockDim.x + threadIdx.x;
    if (i < 4 * 8192) {
        const int w    = i >> 13;
        const int rem  = i & 8191;            // (ntile*8 + kk)*64 + lane
        const int lane = rem & 63;
        const int kk   = (rem >> 6) & 7;
        const int ntile= rem >> 9;
        const int row  = ntile * 16 + (lane & 15);
        const int col  = kk * 32 + (lane >> 4) * 8;
        const float* Wsrc = (w == 0) ? W0 : (w == 1) ? W1 : (w == 2) ? W2 : W3;
        const float* sp = Wsrc + (size_t)row * D_MODEL + col;
        float4 x0 = *(const float4*)sp;
        float4 x1 = *(const float4*)(sp + 4);
        unsigned short* dp = out + (size_t)w * D_MODEL * D_MODEL + (size_t)rem * 8;
        ushort4 o0, o1;
        o0.x = f2bf_rne(x0.x); o0.y = f2bf_rne(x0.y); o0.z = f2bf_rne(x0.z); o0.w = f2bf_rne(x0.w);
        o1.x = f2bf_rne(x1.x); o1.y = f2bf_rne(x1.y); o1.z = f2bf_rne(x1.z); o1.w = f2bf_rne(x1.w);
        *(ushort4*)dp = o0;
        *(ushort4*)(dp + 4) = o1;
    } else {
        const int e = i - 4 * 8192;
        if (e < E) atomicAdd(&counts[dst[e]], 1);
    }
}

// ---------------- persistent-B merged QKV GEMM -----------------------------------
// blockIdx.y selects q/k/v. Each block loads its wave's B-fragments (4 ntiles x
// 8 kk = 32 KB = 128 VGPRs) ONCE, then loops over m-tiles (BM=32): the K-loop
// is pure LDS-read + MFMA (no global loads -> no per-iteration L2 latency).
// kvbuf layout (interleaved for attn's single-dwordx4 gather): node row = 512
// halfwords; halfword 8*l+j = K[4l+j] (j<4), V[4l+(j-4)] (j>=4). So lane l of
// the attn wave reads its K4|V4 as ONE 16B load.
__global__ __launch_bounds__(256, 2) void gemm_qkv(
    const float* __restrict__ Aq, const float* __restrict__ Ak, const float* __restrict__ Av,
    const unsigned short* __restrict__ Wsw,
    const float* __restrict__ bq, const float* __restrict__ bk, const float* __restrict__ bv,
    unsigned short* __restrict__ qbuf, unsigned short* __restrict__ kvbuf,
    int M, int mtiles)
{
    __shared__ __align__(16) unsigned short smem[32 * LDSROW];

    const int which = blockIdx.y;
    const float* A = (which == 0) ? Aq : (which == 1) ? Ak : Av;
    const float* bias = (which == 0) ? bq : (which == 1) ? bk : bv;
    const unsigned short* Wb = Wsw + (size_t)which * D_MODEL * D_MODEL;
    unsigned short* outp = (which == 0) ? qbuf : kvbuf;
    const int voff = (which == 2) ? 4 : 0;   // V lanes sit 4 halfwords after K lanes

    const int lane  = threadIdx.x & 63;
    const int wave  = threadIdx.x >> 6;
    const int mrow  = lane & 15;
    const int quad  = lane >> 4;

    // ---- load B fragments once: [ni][kk], 128 VGPRs ----
    bf16x8 bfr[4][8];
#pragma unroll
    for (int ni = 0; ni < 4; ++ni)
#pragma unroll
        for (int kk = 0; kk < 8; ++kk)
            bfr[ni][kk] = *(const bf16x8*)(Wb + ((size_t)((wave * 4 + ni) * 8 + kk) * 64 + lane) * 8);

    // ---- per-wave column bias (reused every tile) ----
    float bcol[4];
#pragma unroll
    for (int ni = 0; ni < 4; ++ni) bcol[ni] = bias[wave * 64 + ni * 16 + mrow];

    for (int t = blockIdx.x; t < mtiles; t += PBLK) {
        const int m0 = t * 32;

        // ---- stage A tile (32 x 256 fp32) into LDS as bf16 ----
#pragma unroll
        for (int i = 0; i < 8; ++i) {
            const int g = i * 256 + threadIdx.x;     // float4 index
            const int r = g >> 6, c4 = g & 63;
            const int grow = min(m0 + r, M - 1);
            float4 x = *(const float4*)(A + (size_t)grow * D_MODEL + c4 * 4);
            ushort4 o;
            o.x = f2bf_rne(x.x); o.y = f2bf_rne(x.y);
            o.z = f2bf_rne(x.z); o.w = f2bf_rne(x.w);
            *(ushort4*)(smem + r * LDSROW + c4 * 4) = o;
        }
        __syncthreads();

        f32x4 acc[2][4] = {};
#pragma unroll
        for (int kk = 0; kk < 8; ++kk) {
            bf16x8 afr[2];
#pragma unroll
            for (int mi = 0; mi < 2; ++mi)
                afr[mi] = *(const bf16x8*)(smem + (mi * 16 + mrow) * LDSROW + kk * 32 + quad * 8);
#pragma unroll
            for (int mi = 0; mi < 2; ++mi)
#pragma unroll
                for (int ni = 0; ni < 4; ++ni)
                    acc[mi][ni] = __builtin_amdgcn_mfma_f32_16x16x32_bf16(
                        afr[mi], bfr[ni][kk], acc[mi][ni], 0, 0, 0);
        }

        // ---- epilogue: bias + bf16, transpose through LDS, coalesced stores ----
        __syncthreads();
#pragma unroll
        for (int ni = 0; ni < 4; ++ni) {
            const int col = wave * 64 + ni * 16 + mrow;
#pragma unroll
            for (int mi = 0; mi < 2; ++mi)
#pragma unroll
                for (int r = 0; r < 4; ++r)
                    smem[(mi * 16 + quad * 4 + r) * LDSROW + col] =
                        f2bf_rne(acc[mi][ni][r] + bcol[ni]);
        }
        __syncthreads();
#pragma unroll
        for (int i = 0; i < 4; ++i) {
            const int g = i * 256 + threadIdx.x;     // ushort8 chunk index
            const int r = g >> 5, c8 = g & 31;
            const int grow = m0 + r;
            if (grow < M) {
                if (which == 0) {
                    bf16x8 x = *(const bf16x8*)(smem + r * LDSROW + c8 * 8);
                    *(bf16x8*)(outp + (size_t)grow * D_MODEL + c8 * 8) = x;
                } else {
                    // interleaved KV store: chunk covers cols 8*c8..8*c8+7 ->
                    // halfword positions 16*c8+voff+(0..3) and 16*c8+8+voff+(0..3)
                    ushort4 lo = *(const ushort4*)(smem + r * LDSROW + c8 * 8);
                    ushort4 hi = *(const ushort4*)(smem + r * LDSROW + c8 * 8 + 4);
                    unsigned short* base = outp + (size_t)grow * 512 + 16 * c8 + voff;
                    *(ushort4*)base = lo;
                    *(ushort4*)(base + 8) = hi;
                }
            }
        }
        __syncthreads();   // stores read smem; next tile's staging overwrites it
    }
}

// ---------------- persistent-B output GEMM: out = attn(bf16) @ Wo^T + bo (fp32) --
__global__ __launch_bounds__(256, 2) void gemm_out(
    const unsigned short* __restrict__ Ab, const unsigned short* __restrict__ Wb,
    const float* __restrict__ bias, float* __restrict__ outp, int M, int mtiles)
{
    __shared__ __align__(16) char smem_raw[32 * LDSROWF * 4];
    unsigned short* smemA = (unsigned short*)smem_raw;   // 32 x LDSROW bf16 (staging)
    float*          smemF = (float*)smem_raw;            // 32 x LDSROWF f32 (epilogue)

    const int lane  = threadIdx.x & 63;
    const int wave  = threadIdx.x >> 6;
    const int mrow  = lane & 15;
    const int quad  = lane >> 4;

    bf16x8 bfr[4][8];
#pragma unroll
    for (int ni = 0; ni < 4; ++ni)
#pragma unroll
        for (int kk = 0; kk < 8; ++kk)
            bfr[ni][kk] = *(const bf16x8*)(Wb + ((size_t)((wave * 4 + ni) * 8 + kk) * 64 + lane) * 8);

    float bcol[4];
#pragma unroll
    for (int ni = 0; ni < 4; ++ni) bcol[ni] = bias[wave * 64 + ni * 16 + mrow];

    for (int t = blockIdx.x; t < mtiles; t += 3 * PBLK) {
        const int m0 = t * 32;

        // ---- stage A tile (32 x 256 bf16) into LDS ----
#pragma unroll
        for (int i = 0; i < 4; ++i) {
            const int g = i * 256 + threadIdx.x;     // ushort8 index
            const int r = g >> 5, c8 = g & 31;
            const int grow = min(m0 + r, M - 1);
            bf16x8 x = *(const bf16x8*)(Ab + (size_t)grow * D_MODEL + c8 * 8);
            *(bf16x8*)(smemA + r * LDSROW + c8 * 8) = x;
        }
        __syncthreads();

        f32x4 acc[2][4] = {};
#pragma unroll
        for (int kk = 0; kk < 8; ++kk) {
            bf16x8 afr[2];
#pragma unroll
            for (int mi = 0; mi < 2; ++mi)
                afr[mi] = *(const bf16x8*)(smemA + (mi * 16 + mrow) * LDSROW + kk * 32 + quad * 8);
#pragma unroll
            for (int mi = 0; mi < 2; ++mi)
#pragma unroll
                for (int ni = 0; ni < 4; ++ni)
                    acc[mi][ni] = __builtin_amdgcn_mfma_f32_16x16x32_bf16(
                        afr[mi], bfr[ni][kk], acc[mi][ni], 0, 0, 0);
        }

        // ---- epilogue: bias, transpose fp32 through LDS, float4 stores ----
        __syncthreads();
#pragma unroll
        for (int ni = 0; ni < 4; ++ni) {
            const int col = wave * 64 + ni * 16 + mrow;
#pragma unroll
            for (int mi = 0; mi < 2; ++mi)
#pragma unroll
                for (int r = 0; r < 4; ++r)
                    smemF[(mi * 16 + quad * 4 + r) * LDSROWF + col] = acc[mi][ni][r] + bcol[ni];
        }
        __syncthreads();
#pragma unroll
        for (int i = 0; i < 8; ++i) {
            const int g = i * 256 + threadIdx.x;     // float4 chunk index
            const int r = g >> 6, c4 = g & 63;
            const int grow = m0 + r;
            if (grow < M) {
                float4 x = *(const float4*)(smemF + r * LDSROWF + c4 * 4);
                *(float4*)(outp + (size_t)grow * D_MODEL + c4 * 4) = x;
            }
        }
        __syncthreads();
    }
}

// ---------------- CSR construction ----------------
__global__ void block_reduce_kernel(const int* __restrict__ counts, int N,
                                    int* __restrict__ blockSums) {
    const int g = blockIdx.x * 256 + threadIdx.x;
    int v = (g < N) ? counts[g] : 0;
#pragma unroll
    for (int d = 1; d < 64; d <<= 1) v += __shfl_xor(v, d);
    __shared__ int ws[4];
    if ((threadIdx.x & 63) == 0) ws[threadIdx.x >> 6] = v;
    __syncthreads();
    if (threadIdx.x == 0) blockSums[blockIdx.x] = ws[0] + ws[1] + ws[2] + ws[3];
}

__global__ void scan_blocks_kernel(int* __restrict__ blockSums, int G) {
    __shared__ int sh[256];
    const int t = threadIdx.x;
    int v = (t < G) ? blockSums[t] : 0;
    sh[t] = v;
    __syncthreads();
#pragma unroll
    for (int off = 1; off < 256; off <<= 1) {
        int add = (t >= off) ? sh[t - off] : 0;
        __syncthreads();
        sh[t] += add;
        __syncthreads();
    }
    if (t < G) blockSums[t] = sh[t] - v;   // exclusive
}

__global__ void scan_write_kernel(const int* __restrict__ counts, int N,
                                  const int* __restrict__ blockOffsets,
                                  int* __restrict__ offsets) {
    const int g = blockIdx.x * 256 + threadIdx.x;
    const int t = threadIdx.x;
    int v = (g < N) ? counts[g] : 0;
    __shared__ int sh[256];
    sh[t] = v;
    __syncthreads();
#pragma unroll
    for (int off = 1; off < 256; off <<= 1) {
        int add = (t >= off) ? sh[t - off] : 0;
        __syncthreads();
        sh[t] += add;
        __syncthreads();
    }
    if (g <= N) offsets[g] = sh[t] - v + blockOffsets[blockIdx.x];
}

__global__ void fill_kernel(const int* __restrict__ dst, const int* __restrict__ src, int E,
                            const int* __restrict__ offsets, int* __restrict__ cursor,
                            int* __restrict__ ssrc) {
    int i = blockIdx.x * blockDim.x + threadIdx.x;
    if (i < E) {
        int d = dst[i];
        int r = atomicAdd(&cursor[d], 1);
        ssrc[offsets[d] + r] = src[i];
    }
}

// ---------------- per-node online-softmax attention ----------------
// One wave per node. Lane l owns elements 4l..4l+3 (head = l>>3).
// kv layout (interleaved): row s = 512 halfwords, lane l's 16B = K[4l..4l+3]|V[4l..4l+3]
// -> exactly ONE global_load_dwordx4 per lane per edge (1 KB/wave/instruction).
__global__ __launch_bounds__(256) void attn_kernel(
    const unsigned short* __restrict__ qb, const unsigned short* __restrict__ kv,
    const int* __restrict__ offsets, const int* __restrict__ ssrc,
    unsigned short* __restrict__ attn, int N)
{
    const int node = blockIdx.x * 4 + (threadIdx.x >> 6);
    if (node >= N) return;
    const int lane = threadIdx.x & 63;

    ushort4 qu = *(const ushort4*)(qb + (size_t)node * D_MODEL + 4 * lane);
    const float sc = 0.17677669529663689f;  // 1/sqrt(32)
    float qx = bf2f(qu.x) * sc, qy = bf2f(qu.y) * sc,
          qz = bf2f(qu.z) * sc, qw = bf2f(qu.w) * sc;

    float m = -INFINITY, l = 0.f;
    float ax = 0.f, ay = 0.f, az = 0.f, aw = 0.f;

    const int e0 = offsets[node], e1 = offsets[node + 1];
    int e = e0;

    // ---- 8-edge stage: 8 independent 16B gathers in flight (latency hiding) ----
    for (; e + 7 < e1; e += 8) {
        u16x8 a0 = *(const u16x8*)(kv + (size_t)ssrc[e]     * 512 + 8 * lane);
        u16x8 a1 = *(const u16x8*)(kv + (size_t)ssrc[e + 1] * 512 + 8 * lane);
        u16x8 a2 = *(const u16x8*)(kv + (size_t)ssrc[e + 2] * 512 + 8 * lane);
        u16x8 a3 = *(const u16x8*)(kv + (size_t)ssrc[e + 3] * 512 + 8 * lane);
        u16x8 a4 = *(const u16x8*)(kv + (size_t)ssrc[e + 4] * 512 + 8 * lane);
        u16x8 a5 = *(const u16x8*)(kv + (size_t)ssrc[e + 5] * 512 + 8 * lane);
        u16x8 a6 = *(const u16x8*)(kv + (size_t)ssrc[e + 6] * 512 + 8 * lane);
        u16x8 a7 = *(const u16x8*)(kv + (size_t)ssrc[e + 7] * 512 + 8 * lane);

        float p0 = qx * bf2f(a0[0]) + qy * bf2f(a0[1]) + qz * bf2f(a0[2]) + qw * bf2f(a0[3]);
        float p1 = qx * bf2f(a1[0]) + qy * bf2f(a1[1]) + qz * bf2f(a1[2]) + qw * bf2f(a1[3]);
        float p2 = qx * bf2f(a2[0]) + qy * bf2f(a2[1]) + qz * bf2f(a2[2]) + qw * bf2f(a2[3]);
        float p3 = qx * bf2f(a3[0]) + qy * bf2f(a3[1]) + qz * bf2f(a3[2]) + qw * bf2f(a3[3]);
        float p4 = qx * bf2f(a4[0]) + qy * bf2f(a4[1]) + qz * bf2f(a4[2]) + qw * bf2f(a4[3]);
        float p5 = qx * bf2f(a5[0]) + qy * bf2f(a5[1]) + qz * bf2f(a5[2]) + qw * bf2f(a5[3]);
        float p6 = qx * bf2f(a6[0]) + qy * bf2f(a6[1]) + qz * bf2f(a6[2]) + qw * bf2f(a6[3]);
        float p7 = qx * bf2f(a7[0]) + qy * bf2f(a7[1]) + qz * bf2f(a7[2]) + qw * bf2f(a7[3]);
#pragma unroll
        for (int d = 1; d <= 4; d <<= 1) {
            p0 += __shfl_xor(p0, d); p1 += __shfl_xor(p1, d);
            p2 += __shfl_xor(p2, d); p3 += __shfl_xor(p3, d);
            p4 += __shfl_xor(p4, d); p5 += __shfl_xor(p5, d);
            p6 += __shfl_xor(p6, d); p7 += __shfl_xor(p7, d);
        }
        float mnew = fmaxf(fmaxf(fmaxf(fmaxf(m, p0), fmaxf(p1, p2)), fmaxf(fmaxf(p3, p4), fmaxf(p5, p6))), p7);
        float alpha = __expf(m - mnew);     // 0 on first group (m=-inf)
        float w0 = __expf(p0 - mnew), w1 = __expf(p1 - mnew);
        float w2 = __expf(p2 - mnew), w3 = __expf(p3 - mnew);
        float w4 = __expf(p4 - mnew), w5 = __expf(p5 - mnew);
        float w6 = __expf(p6 - mnew), w7 = __expf(p7 - mnew);
        ax = ax * alpha + w0 * bf2f(a0[4]) + w1 * bf2f(a1[4]) + w2 * bf2f(a2[4]) + w3 * bf2f(a3[4])
                        + w4 * bf2f(a4[4]) + w5 * bf2f(a5[4]) + w6 * bf2f(a6[4]) + w7 * bf2f(a7[4]);
        ay = ay * alpha + w0 * bf2f(a0[5]) + w1 * bf2f(a1[5]) + w2 * bf2f(a2[5]) + w3 * bf2f(a3[5])
                        + w4 * bf2f(a4[5]) + w5 * bf2f(a5[5]) + w6 * bf2f(a6[5]) + w7 * bf2f(a7[5]);
        az = az * alpha + w0 * bf2f(a0[6]) + w1 * bf2f(a1[6]) + w2 * bf2f(a2[6]) + w3 * bf2f(a3[6])
                        + w4 * bf2f(a4[6]) + w5 * bf2f(a5[6]) + w6 * bf2f(a6[6]) + w7 * bf2f(a7[6]);
        aw = aw * alpha + w0 * bf2f(a0[7]) + w1 * bf2f(a1[7]) + w2 * bf2f(a2[7]) + w3 * bf2f(a3[7])
                        + w4 * bf2f(a4[7]) + w5 * bf2f(a5[7]) + w6 * bf2f(a6[7]) + w7 * bf2f(a7[7]);
        l = l * alpha + w0 + w1 + w2 + w3 + w4 + w5 + w6 + w7;
        m = mnew;
    }

    // ---- 4-edge stage ----
    for (; e + 3 < e1; e += 4) {
        u16x8 a0 = *(const u16x8*)(kv + (size_t)ssrc[e]     * 512 + 8 * lane);
        u16x8 a1 = *(const u16x8*)(kv + (size_t)ssrc[e + 1] * 512 + 8 * lane);
        u16x8 a2 = *(const u16x8*)(kv + (size_t)ssrc[e + 2] * 512 + 8 * lane);
        u16x8 a3 = *(const u16x8*)(kv + (size_t)ssrc[e + 3] * 512 + 8 * lane);

        float p0 = qx * bf2f(a0[0]) + qy * bf2f(a0[1]) + qz * bf2f(a0[2]) + qw * bf2f(a0[3]);
        float p1 = qx * bf2f(a1[0]) + qy * bf2f(a1[1]) + qz * bf2f(a1[2]) + qw * bf2f(a1[3]);
        float p2 = qx * bf2f(a2[0]) + qy * bf2f(a2[1]) + qz * bf2f(a2[2]) + qw * bf2f(a2[3]);
        float p3 = qx * bf2f(a3[0]) + qy * bf2f(a3[1]) + qz * bf2f(a3[2]) + qw * bf2f(a3[3]);
#pragma unroll
        for (int d = 1; d <= 4; d <<= 1) {
            p0 += __shfl_xor(p0, d); p1 += __shfl_xor(p1, d);
            p2 += __shfl_xor(p2, d); p3 += __shfl_xor(p3, d);
        }
        float mnew = fmaxf(fmaxf(fmaxf(m, p0), fmaxf(p1, p2)), p3);
        float alpha = __expf(m - mnew);
        float w0 = __expf(p0 - mnew), w1 = __expf(p1 - mnew);
        float w2 = __expf(p2 - mnew), w3 = __expf(p3 - mnew);
        ax = ax * alpha + w0 * bf2f(a0[4]) + w1 * bf2f(a1[4]) + w2 * bf2f(a2[4]) + w3 * bf2f(a3[4]);
        ay = ay * alpha + w0 * bf2f(a0[5]) + w1 * bf2f(a1[5]) + w2 * bf2f(a2[5]) + w3 * bf2f(a3[5]);
        az = az * alpha + w0 * bf2f(a0[6]) + w1 * bf2f(a1[6]) + w2 * bf2f(a2[6]) + w3 * bf2f(a3[6]);
        aw = aw * alpha + w0 * bf2f(a0[7]) + w1 * bf2f(a1[7]) + w2 * bf2f(a2[7]) + w3 * bf2f(a3[7]);
        l = l * alpha + w0 + w1 + w2 + w3;
        m = mnew;
    }

    // ---- scalar tail ----
    for (; e < e1; ++e) {
        int s = ssrc[e];
        u16x8 a = *(const u16x8*)(kv + (size_t)s * 512 + 8 * lane);
        float p = qx * bf2f(a[0]) + qy * bf2f(a[1]) + qz * bf2f(a[2]) + qw * bf2f(a[3]);
        p += __shfl_xor(p, 1);
        p += __shfl_xor(p, 2);
        p += __shfl_xor(p, 4);
        float mnew  = fmaxf(m, p);
        float alpha = __expf(m - mnew);
        float w     = __expf(p - mnew);
        ax = ax * alpha + w * bf2f(a[4]);
        ay = ay * alpha + w * bf2f(a[5]);
        az = az * alpha + w * bf2f(a[6]);
        aw = aw * alpha + w * bf2f(a[7]);
        l = l * alpha + w;
        m = mnew;
    }

    const float inv = (l > 0.f) ? 1.f / l : 0.f;  // deg-0 nodes -> zeros
    ushort4 o;
    o.x = f2bf_rne(ax * inv);
    o.y = f2bf_rne(ay * inv);
    o.z = f2bf_rne(az * inv);
    o.w = f2bf_rne(aw * inv);
    *(ushort4*)(attn + (size_t)node * D_MODEL + 4 * lane) = o;
}

// ---------------- launch ----------------
extern "C" void kernel_launch(void* const* d_in, const int* in_sizes, int n_in,
                              void* d_out, int out_size, void* d_ws, size_t ws_size,
                              hipStream_t stream)
{
    const float* query = (const float*)d_in[0];
    const float* key   = (const float*)d_in[1];
    const float* value = (const float*)d_in[2];
    const int*   edges = (const int*)d_in[3];
    const float* Wq = (const float*)d_in[4];
    const float* bq = (const float*)d_in[5];
    const float* Wk = (const float*)d_in[6];
    const float* bk = (const float*)d_in[7];
    const float* Wv = (const float*)d_in[8];
    const float* bv = (const float*)d_in[9];
    const float* Wo = (const float*)d_in[10];
    const float* bo = (const float*)d_in[11];
    float* out = (float*)d_out;

    const int N = in_sizes[0] / D_MODEL;
    const int E = in_sizes[3] / 2;
    const int* dst = edges;
    const int* src = edges + E;

    char* ws = (char*)d_ws;
    size_t off = 0;
    auto alloc = [&](size_t bytes) {
        void* p = ws + off;
        off += (bytes + 255) & ~(size_t)255;
        return p;
    };
    unsigned short* qbuf  = (unsigned short*)alloc((size_t)N * D_MODEL * 2);
    unsigned short* kvbuf = (unsigned short*)alloc((size_t)N * 2 * D_MODEL * 2); // K|V interleaved
    unsigned short* attnb = (unsigned short*)alloc((size_t)N * D_MODEL * 2);
    unsigned short* Wbuf  = (unsigned short*)alloc((size_t)4 * D_MODEL * D_MODEL * 2);
    int*            counts  = (int*)alloc((size_t)2 * N * 4);   // counts + cursor contiguous
    int*            offsets = (int*)alloc((size_t)(N + 1) * 4);
    int*            ssrc    = (int*)alloc((size_t)E * 4);
    int*            bsums   = (int*)alloc((size_t)256 * 4);

    hipMemsetAsync(counts, 0, (size_t)2 * N * 4, stream);

    // fused weight-convert + histogram (independent work)
    const int fused_threads = 4 * 8192 + E;
    conv_weights_hist<<<(fused_threads + 255) / 256, 256, 0, stream>>>(
        Wq, Wk, Wv, Wo, Wbuf, dst, E, counts);

    const int mtiles = (N + 31) / 32;
    gemm_qkv<<<dim3(PBLK, 3), 256, 0, stream>>>(query, key, value, Wbuf,
                                                bq, bk, bv, qbuf, kvbuf, N, mtiles);

    const int G = (N + 256) / 256;  // ceil((N+1)/256)
    block_reduce_kernel<<<G, 256, 0, stream>>>(counts, N, bsums);
    scan_blocks_kernel<<<1, 256, 0, stream>>>(bsums, G);
    scan_write_kernel<<<G, 256, 0, stream>>>(counts, N, bsums, offsets);

    const int eblocks = (E + 255) / 256;
    fill_kernel<<<eblocks, 256, 0, stream>>>(dst, src, E, offsets, counts + N, ssrc);
    attn_kernel<<<(N + 3) / 4, 256, 0, stream>>>(qbuf, kvbuf, offsets, ssrc, attnb, N);

    gemm_out<<<3 * PBLK, 256, 0, stream>>>(attnb, Wbuf + 3 * D_MODEL * D_MODEL, bo, out, N, mtiles);
}

// Round 2
// 366.387 us; speedup vs baseline: 1.0086x; 1.0086x over previous
//
#include <hip/hip_runtime.h>
#include <hip/hip_bf16.h>
#include <cstdint>

#define D_MODEL 256
#define NHEADS 8
#define DK 32
#define LDSPAD 8
#define LDSROW (D_MODEL + LDSPAD)   // 264 bf16 per LDS row
#define LDSROWF (D_MODEL + 4)       // 260 f32 per LDS row (gemm_out epilogue)
#define QBLK 168                    // gemm_qkv x-blocks; %8==0 so (x,y=1),(x,y=2) share an XCD
#define OBLK 512                    // gemm_out blocks (2/CU at 8 waves)

typedef float f32x4 __attribute__((ext_vector_type(4)));
typedef __bf16 bf16x8 __attribute__((ext_vector_type(8)));
typedef unsigned short u16x8 __attribute__((ext_vector_type(8)));

__device__ __forceinline__ unsigned short f2bf_rne(float f) {
    unsigned int u = __float_as_uint(f);
    u += 0x7FFF + ((u >> 16) & 1);
    return (unsigned short)(u >> 16);
}
__device__ __forceinline__ float bf2f(unsigned short h) {
    return __uint_as_float(((unsigned int)h) << 16);
}

// ---------------- weight fp32 -> bf16 (MFMA B-fragment order) + edge histogram --
__global__ void conv_weights_hist(const float* __restrict__ W0, const float* __restrict__ W1,
                                  const float* __restrict__ W2, const float* __restrict__ W3,
                                  unsigned short* __restrict__ out,
                                  const int* __restrict__ dst, int E,
                                  int* __restrict__ counts) {
    int i = blockIdx.x * blockDim.x + threadIdx.x;
    if (i < 4 * 8192) {
        const int w    = i >> 13;
        const int rem  = i & 8191;            // (ntile*8 + kk)*64 + lane
        const int lane = rem & 63;
        const int kk   = (rem >> 6) & 7;
        const int ntile= rem >> 9;
        const int row  = ntile * 16 + (lane & 15);
        const int col  = kk * 32 + (lane >> 4) * 8;
        const float* Wsrc = (w == 0) ? W0 : (w == 1) ? W1 : (w == 2) ? W2 : W3;
        const float* sp = Wsrc + (size_t)row * D_MODEL + col;
        float4 x0 = *(const float4*)sp;
        float4 x1 = *(const float4*)(sp + 4);
        unsigned short* dp = out + (size_t)w * D_MODEL * D_MODEL + (size_t)rem * 8;
        ushort4 o0, o1;
        o0.x = f2bf_rne(x0.x); o0.y = f2bf_rne(x0.y); o0.z = f2bf_rne(x0.z); o0.w = f2bf_rne(x0.w);
        o1.x = f2bf_rne(x1.x); o1.y = f2bf_rne(x1.y); o1.z = f2bf_rne(x1.z); o1.w = f2bf_rne(x1.w);
        *(ushort4*)dp = o0;
        *(ushort4*)(dp + 4) = o1;
    } else {
        const int e = i - 4 * 8192;
        if (e < E) atomicAdd(&counts[dst[e]], 1);
    }
}

// ---------------- persistent-B merged QKV GEMM (8-wave, reg-prefetch pipeline) ---
// blockIdx.y selects q/k/v. 512 threads = 8 waves; each wave owns 2 n-tiles
// (bfr[2][8] = 64 VGPR resident weights). Next m-tile's A is prefetched into
// registers during the MFMA K-loop + epilogue (T14 async-stage: reg loads are
// not drained at __syncthreads).
// kvbuf layout (interleaved for attn's single-dwordx4 gather): node row = 512
// halfwords; halfword 8*l+j = K[4l+j] (j<4), V[4l+(j-4)] (j>=4).
__global__ __launch_bounds__(512, 4) void gemm_qkv(
    const float* __restrict__ Aq, const float* __restrict__ Ak, const float* __restrict__ Av,
    const unsigned short* __restrict__ Wsw,
    const float* __restrict__ bq, const float* __restrict__ bk, const float* __restrict__ bv,
    unsigned short* __restrict__ qbuf, unsigned short* __restrict__ kvbuf,
    int M, int mtiles)
{
    __shared__ __align__(16) unsigned short smem[32 * LDSROW];   // 16.9 KB

    const int which = blockIdx.y;
    const float* A = (which == 0) ? Aq : (which == 1) ? Ak : Av;
    const float* bias = (which == 0) ? bq : (which == 1) ? bk : bv;
    const unsigned short* Wb = Wsw + (size_t)which * D_MODEL * D_MODEL;
    unsigned short* outp = (which == 0) ? qbuf : kvbuf;
    const int voff = (which == 2) ? 4 : 0;   // V lanes sit 4 halfwords after K lanes

    const int lane  = threadIdx.x & 63;
    const int wave  = threadIdx.x >> 6;      // 0..7
    const int mrow  = lane & 15;
    const int quad  = lane >> 4;

    // ---- resident B fragments: 2 n-tiles x 8 kk = 64 VGPRs ----
    bf16x8 bfr[2][8];
#pragma unroll
    for (int ni = 0; ni < 2; ++ni)
#pragma unroll
        for (int kk = 0; kk < 8; ++kk)
            bfr[ni][kk] = *(const bf16x8*)(Wb + ((size_t)((wave * 2 + ni) * 8 + kk) * 64 + lane) * 8);

    float bcol[2];
#pragma unroll
    for (int ni = 0; ni < 2; ++ni) bcol[ni] = bias[wave * 32 + ni * 16 + mrow];

    int t = blockIdx.x;
    float4 pf[4];
    if (t < mtiles) {
        const int m0 = t * 32;
#pragma unroll
        for (int i = 0; i < 4; ++i) {
            const int g = i * 512 + threadIdx.x;     // float4 index 0..2047
            const int r = g >> 6, c4 = g & 63;
            const int grow = min(m0 + r, M - 1);
            pf[i] = *(const float4*)(A + (size_t)grow * D_MODEL + c4 * 4);
        }
    }

    for (; t < mtiles; t += QBLK) {
        const int m0 = t * 32;

        // ---- write prefetched A tile (32 x 256) into LDS as bf16 ----
#pragma unroll
        for (int i = 0; i < 4; ++i) {
            const int g = i * 512 + threadIdx.x;
            const int r = g >> 6, c4 = g & 63;
            ushort4 o;
            o.x = f2bf_rne(pf[i].x); o.y = f2bf_rne(pf[i].y);
            o.z = f2bf_rne(pf[i].z); o.w = f2bf_rne(pf[i].w);
            *(ushort4*)(smem + r * LDSROW + c4 * 4) = o;
        }
        __syncthreads();

        // ---- issue next tile's loads; latency hides under MFMA + epilogue ----
        const int tn = t + QBLK;
        if (tn < mtiles) {
            const int m0n = tn * 32;
#pragma unroll
            for (int i = 0; i < 4; ++i) {
                const int g = i * 512 + threadIdx.x;
                const int r = g >> 6, c4 = g & 63;
                const int grow = min(m0n + r, M - 1);
                pf[i] = *(const float4*)(A + (size_t)grow * D_MODEL + c4 * 4);
            }
        }

        f32x4 acc[2][2] = {};
#pragma unroll
        for (int kk = 0; kk < 8; ++kk) {
            bf16x8 afr[2];
#pragma unroll
            for (int mi = 0; mi < 2; ++mi)
                afr[mi] = *(const bf16x8*)(smem + (mi * 16 + mrow) * LDSROW + kk * 32 + quad * 8);
#pragma unroll
            for (int mi = 0; mi < 2; ++mi)
#pragma unroll
                for (int ni = 0; ni < 2; ++ni)
                    acc[mi][ni] = __builtin_amdgcn_mfma_f32_16x16x32_bf16(
                        afr[mi], bfr[ni][kk], acc[mi][ni], 0, 0, 0);
        }

        // ---- epilogue: bias + bf16, transpose through LDS, coalesced stores ----
        __syncthreads();
#pragma unroll
        for (int ni = 0; ni < 2; ++ni) {
            const int col = wave * 32 + ni * 16 + mrow;
#pragma unroll
            for (int mi = 0; mi < 2; ++mi)
#pragma unroll
                for (int r = 0; r < 4; ++r)
                    smem[(mi * 16 + quad * 4 + r) * LDSROW + col] =
                        f2bf_rne(acc[mi][ni][r] + bcol[ni]);
        }
        __syncthreads();
#pragma unroll
        for (int i = 0; i < 2; ++i) {
            const int g = i * 512 + threadIdx.x;     // ushort8 chunk index 0..1023
            const int r = g >> 5, c8 = g & 31;
            const int grow = m0 + r;
            if (grow < M) {
                if (which == 0) {
                    bf16x8 x = *(const bf16x8*)(smem + r * LDSROW + c8 * 8);
                    *(bf16x8*)(outp + (size_t)grow * D_MODEL + c8 * 8) = x;
                } else {
                    ushort4 lo = *(const ushort4*)(smem + r * LDSROW + c8 * 8);
                    ushort4 hi = *(const ushort4*)(smem + r * LDSROW + c8 * 8 + 4);
                    unsigned short* base = outp + (size_t)grow * 512 + 16 * c8 + voff;
                    *(ushort4*)base = lo;
                    *(ushort4*)(base + 8) = hi;
                }
            }
        }
        __syncthreads();   // stores read smem; next tile's staging overwrites it
    }
}

// ---------------- persistent-B output GEMM (8-wave, reg-prefetch pipeline) ------
__global__ __launch_bounds__(512, 4) void gemm_out(
    const unsigned short* __restrict__ Ab, const unsigned short* __restrict__ Wb,
    const float* __restrict__ bias, float* __restrict__ outp, int M, int mtiles)
{
    __shared__ __align__(16) char smem_raw[32 * LDSROWF * 4];    // 33.3 KB
    unsigned short* smemA = (unsigned short*)smem_raw;   // 32 x LDSROW bf16 (staging)
    float*          smemF = (float*)smem_raw;            // 32 x LDSROWF f32 (epilogue)

    const int lane  = threadIdx.x & 63;
    const int wave  = threadIdx.x >> 6;
    const int mrow  = lane & 15;
    const int quad  = lane >> 4;

    bf16x8 bfr[2][8];
#pragma unroll
    for (int ni = 0; ni < 2; ++ni)
#pragma unroll
        for (int kk = 0; kk < 8; ++kk)
            bfr[ni][kk] = *(const bf16x8*)(Wb + ((size_t)((wave * 2 + ni) * 8 + kk) * 64 + lane) * 8);

    float bcol[2];
#pragma unroll
    for (int ni = 0; ni < 2; ++ni) bcol[ni] = bias[wave * 32 + ni * 16 + mrow];

    int t = blockIdx.x;
    bf16x8 pf[2];
    if (t < mtiles) {
        const int m0 = t * 32;
#pragma unroll
        for (int i = 0; i < 2; ++i) {
            const int g = i * 512 + threadIdx.x;     // ushort8 index 0..1023
            const int r = g >> 5, c8 = g & 31;
            const int grow = min(m0 + r, M - 1);
            pf[i] = *(const bf16x8*)(Ab + (size_t)grow * D_MODEL + c8 * 8);
        }
    }

    for (; t < mtiles; t += OBLK) {
        const int m0 = t * 32;

        // ---- write prefetched A tile into LDS ----
#pragma unroll
        for (int i = 0; i < 2; ++i) {
            const int g = i * 512 + threadIdx.x;
            const int r = g >> 5, c8 = g & 31;
            *(bf16x8*)(smemA + r * LDSROW + c8 * 8) = pf[i];
        }
        __syncthreads();

        const int tn = t + OBLK;
        if (tn < mtiles) {
            const int m0n = tn * 32;
#pragma unroll
            for (int i = 0; i < 2; ++i) {
                const int g = i * 512 + threadIdx.x;
                const int r = g >> 5, c8 = g & 31;
                const int grow = min(m0n + r, M - 1);
                pf[i] = *(const bf16x8*)(Ab + (size_t)grow * D_MODEL + c8 * 8);
            }
        }

        f32x4 acc[2][2] = {};
#pragma unroll
        for (int kk = 0; kk < 8; ++kk) {
            bf16x8 afr[2];
#pragma unroll
            for (int mi = 0; mi < 2; ++mi)
                afr[mi] = *(const bf16x8*)(smemA + (mi * 16 + mrow) * LDSROW + kk * 32 + quad * 8);
#pragma unroll
            for (int mi = 0; mi < 2; ++mi)
#pragma unroll
                for (int ni = 0; ni < 2; ++ni)
                    acc[mi][ni] = __builtin_amdgcn_mfma_f32_16x16x32_bf16(
                        afr[mi], bfr[ni][kk], acc[mi][ni], 0, 0, 0);
        }

        // ---- epilogue: bias, transpose fp32 through LDS, float4 stores ----
        __syncthreads();
#pragma unroll
        for (int ni = 0; ni < 2; ++ni) {
            const int col = wave * 32 + ni * 16 + mrow;
#pragma unroll
            for (int mi = 0; mi < 2; ++mi)
#pragma unroll
                for (int r = 0; r < 4; ++r)
                    smemF[(mi * 16 + quad * 4 + r) * LDSROWF + col] = acc[mi][ni][r] + bcol[ni];
        }
        __syncthreads();
#pragma unroll
        for (int i = 0; i < 4; ++i) {
            const int g = i * 512 + threadIdx.x;     // float4 chunk index 0..2047
            const int r = g >> 6, c4 = g & 63;
            const int grow = m0 + r;
            if (grow < M) {
                float4 x = *(const float4*)(smemF + r * LDSROWF + c4 * 4);
                *(float4*)(outp + (size_t)grow * D_MODEL + c4 * 4) = x;
            }
        }
        __syncthreads();
    }
}

// ---------------- CSR construction ----------------
__global__ void block_reduce_kernel(const int* __restrict__ counts, int N,
                                    int* __restrict__ blockSums) {
    const int g = blockIdx.x * 256 + threadIdx.x;
    int v = (g < N) ? counts[g] : 0;
#pragma unroll
    for (int d = 1; d < 64; d <<= 1) v += __shfl_xor(v, d);
    __shared__ int ws[4];
    if ((threadIdx.x & 63) == 0) ws[threadIdx.x >> 6] = v;
    __syncthreads();
    if (threadIdx.x == 0) blockSums[blockIdx.x] = ws[0] + ws[1] + ws[2] + ws[3];
}

__global__ void scan_blocks_kernel(int* __restrict__ blockSums, int G) {
    __shared__ int sh[256];
    const int t = threadIdx.x;
    int v = (t < G) ? blockSums[t] : 0;
    sh[t] = v;
    __syncthreads();
#pragma unroll
    for (int off = 1; off < 256; off <<= 1) {
        int add = (t >= off) ? sh[t - off] : 0;
        __syncthreads();
        sh[t] += add;
        __syncthreads();
    }
    if (t < G) blockSums[t] = sh[t] - v;   // exclusive
}

__global__ void scan_write_kernel(const int* __restrict__ counts, int N,
                                  const int* __restrict__ blockOffsets,
                                  int* __restrict__ offsets) {
    const int g = blockIdx.x * 256 + threadIdx.x;
    const int t = threadIdx.x;
    int v = (g < N) ? counts[g] : 0;
    __shared__ int sh[256];
    sh[t] = v;
    __syncthreads();
#pragma unroll
    for (int off = 1; off < 256; off <<= 1) {
        int add = (t >= off) ? sh[t - off] : 0;
        __syncthreads();
        sh[t] += add;
        __syncthreads();
    }
    if (g <= N) offsets[g] = sh[t] - v + blockOffsets[blockIdx.x];
}

__global__ void fill_kernel(const int* __restrict__ dst, const int* __restrict__ src, int E,
                            const int* __restrict__ offsets, int* __restrict__ cursor,
                            int* __restrict__ ssrc) {
    int i = blockIdx.x * blockDim.x + threadIdx.x;
    if (i < E) {
        int d = dst[i];
        int r = atomicAdd(&cursor[d], 1);
        ssrc[offsets[d] + r] = src[i];
    }
}

// ---------------- per-node online-softmax attention ----------------
// One wave per node. Lane l owns elements 4l..4l+3 (head = l>>3).
// kv layout (interleaved): row s = 512 halfwords, lane l's 16B = K[4l..4l+3]|V[4l..4l+3]
__global__ __launch_bounds__(256) void attn_kernel(
    const unsigned short* __restrict__ qb, const unsigned short* __restrict__ kv,
    const int* __restrict__ offsets, const int* __restrict__ ssrc,
    unsigned short* __restrict__ attn, int N)
{
    const int node = blockIdx.x * 4 + (threadIdx.x >> 6);
    if (node >= N) return;
    const int lane = threadIdx.x & 63;

    ushort4 qu = *(const ushort4*)(qb + (size_t)node * D_MODEL + 4 * lane);
    const float sc = 0.17677669529663689f;  // 1/sqrt(32)
    float qx = bf2f(qu.x) * sc, qy = bf2f(qu.y) * sc,
          qz = bf2f(qu.z) * sc, qw = bf2f(qu.w) * sc;

    float m = -INFINITY, l = 0.f;
    float ax = 0.f, ay = 0.f, az = 0.f, aw = 0.f;

    const int e0 = offsets[node], e1 = offsets[node + 1];
    int e = e0;

    // ---- 8-edge stage: 8 independent 16B gathers in flight ----
    for (; e + 7 < e1; e += 8) {
        u16x8 a0 = *(const u16x8*)(kv + (size_t)ssrc[e]     * 512 + 8 * lane);
        u16x8 a1 = *(const u16x8*)(kv + (size_t)ssrc[e + 1] * 512 + 8 * lane);
        u16x8 a2 = *(const u16x8*)(kv + (size_t)ssrc[e + 2] * 512 + 8 * lane);
        u16x8 a3 = *(const u16x8*)(kv + (size_t)ssrc[e + 3] * 512 + 8 * lane);
        u16x8 a4 = *(const u16x8*)(kv + (size_t)ssrc[e + 4] * 512 + 8 * lane);
        u16x8 a5 = *(const u16x8*)(kv + (size_t)ssrc[e + 5] * 512 + 8 * lane);
        u16x8 a6 = *(const u16x8*)(kv + (size_t)ssrc[e + 6] * 512 + 8 * lane);
        u16x8 a7 = *(const u16x8*)(kv + (size_t)ssrc[e + 7] * 512 + 8 * lane);

        float p0 = qx * bf2f(a0[0]) + qy * bf2f(a0[1]) + qz * bf2f(a0[2]) + qw * bf2f(a0[3]);
        float p1 = qx * bf2f(a1[0]) + qy * bf2f(a1[1]) + qz * bf2f(a1[2]) + qw * bf2f(a1[3]);
        float p2 = qx * bf2f(a2[0]) + qy * bf2f(a2[1]) + qz * bf2f(a2[2]) + qw * bf2f(a2[3]);
        float p3 = qx * bf2f(a3[0]) + qy * bf2f(a3[1]) + qz * bf2f(a3[2]) + qw * bf2f(a3[3]);
        float p4 = qx * bf2f(a4[0]) + qy * bf2f(a4[1]) + qz * bf2f(a4[2]) + qw * bf2f(a4[3]);
        float p5 = qx * bf2f(a5[0]) + qy * bf2f(a5[1]) + qz * bf2f(a5[2]) + qw * bf2f(a5[3]);
        float p6 = qx * bf2f(a6[0]) + qy * bf2f(a6[1]) + qz * bf2f(a6[2]) + qw * bf2f(a6[3]);
        float p7 = qx * bf2f(a7[0]) + qy * bf2f(a7[1]) + qz * bf2f(a7[2]) + qw * bf2f(a7[3]);
#pragma unroll
        for (int d = 1; d <= 4; d <<= 1) {
            p0 += __shfl_xor(p0, d); p1 += __shfl_xor(p1, d);
            p2 += __shfl_xor(p2, d); p3 += __shfl_xor(p3, d);
            p4 += __shfl_xor(p4, d); p5 += __shfl_xor(p5, d);
            p6 += __shfl_xor(p6, d); p7 += __shfl_xor(p7, d);
        }
        float mnew = fmaxf(fmaxf(fmaxf(fmaxf(m, p0), fmaxf(p1, p2)), fmaxf(fmaxf(p3, p4), fmaxf(p5, p6))), p7);
        float alpha = __expf(m - mnew);
        float w0 = __expf(p0 - mnew), w1 = __expf(p1 - mnew);
        float w2 = __expf(p2 - mnew), w3 = __expf(p3 - mnew);
        float w4 = __expf(p4 - mnew), w5 = __expf(p5 - mnew);
        float w6 = __expf(p6 - mnew), w7 = __expf(p7 - mnew);
        ax = ax * alpha + w0 * bf2f(a0[4]) + w1 * bf2f(a1[4]) + w2 * bf2f(a2[4]) + w3 * bf2f(a3[4])
                        + w4 * bf2f(a4[4]) + w5 * bf2f(a5[4]) + w6 * bf2f(a6[4]) + w7 * bf2f(a7[4]);
        ay = ay * alpha + w0 * bf2f(a0[5]) + w1 * bf2f(a1[5]) + w2 * bf2f(a2[5]) + w3 * bf2f(a3[5])
                        + w4 * bf2f(a4[5]) + w5 * bf2f(a5[5]) + w6 * bf2f(a6[5]) + w7 * bf2f(a7[5]);
        az = az * alpha + w0 * bf2f(a0[6]) + w1 * bf2f(a1[6]) + w2 * bf2f(a2[6]) + w3 * bf2f(a3[6])
                        + w4 * bf2f(a4[6]) + w5 * bf2f(a5[6]) + w6 * bf2f(a6[6]) + w7 * bf2f(a7[6]);
        aw = aw * alpha + w0 * bf2f(a0[7]) + w1 * bf2f(a1[7]) + w2 * bf2f(a2[7]) + w3 * bf2f(a3[7])
                        + w4 * bf2f(a4[7]) + w5 * bf2f(a5[7]) + w6 * bf2f(a6[7]) + w7 * bf2f(a7[7]);
        l = l * alpha + w0 + w1 + w2 + w3 + w4 + w5 + w6 + w7;
        m = mnew;
    }

    // ---- 4-edge stage ----
    for (; e + 3 < e1; e += 4) {
        u16x8 a0 = *(const u16x8*)(kv + (size_t)ssrc[e]     * 512 + 8 * lane);
        u16x8 a1 = *(const u16x8*)(kv + (size_t)ssrc[e + 1] * 512 + 8 * lane);
        u16x8 a2 = *(const u16x8*)(kv + (size_t)ssrc[e + 2] * 512 + 8 * lane);
        u16x8 a3 = *(const u16x8*)(kv + (size_t)ssrc[e + 3] * 512 + 8 * lane);

        float p0 = qx * bf2f(a0[0]) + qy * bf2f(a0[1]) + qz * bf2f(a0[2]) + qw * bf2f(a0[3]);
        float p1 = qx * bf2f(a1[0]) + qy * bf2f(a1[1]) + qz * bf2f(a1[2]) + qw * bf2f(a1[3]);
        float p2 = qx * bf2f(a2[0]) + qy * bf2f(a2[1]) + qz * bf2f(a2[2]) + qw * bf2f(a2[3]);
        float p3 = qx * bf2f(a3[0]) + qy * bf2f(a3[1]) + qz * bf2f(a3[2]) + qw * bf2f(a3[3]);
#pragma unroll
        for (int d = 1; d <= 4; d <<= 1) {
            p0 += __shfl_xor(p0, d); p1 += __shfl_xor(p1, d);
            p2 += __shfl_xor(p2, d); p3 += __shfl_xor(p3, d);
        }
        float mnew = fmaxf(fmaxf(fmaxf(m, p0), fmaxf(p1, p2)), p3);
        float alpha = __expf(m - mnew);
        float w0 = __expf(p0 - mnew), w1 = __expf(p1 - mnew);
        float w2 = __expf(p2 - mnew), w3 = __expf(p3 - mnew);
        ax = ax * alpha + w0 * bf2f(a0[4]) + w1 * bf2f(a1[4]) + w2 * bf2f(a2[4]) + w3 * bf2f(a3[4]);
        ay = ay * alpha + w0 * bf2f(a0[5]) + w1 * bf2f(a1[5]) + w2 * bf2f(a2[5]) + w3 * bf2f(a3[5]);
        az = az * alpha + w0 * bf2f(a0[6]) + w1 * bf2f(a1[6]) + w2 * bf2f(a2[6]) + w3 * bf2f(a3[6]);
        aw = aw * alpha + w0 * bf2f(a0[7]) + w1 * bf2f(a1[7]) + w2 * bf2f(a2[7]) + w3 * bf2f(a3[7]);
        l = l * alpha + w0 + w1 + w2 + w3;
        m = mnew;
    }

    // ---- scalar tail ----
    for (; e < e1; ++e) {
        int s = ssrc[e];
        u16x8 a = *(const u16x8*)(kv + (size_t)s * 512 + 8 * lane);
        float p = qx * bf2f(a[0]) + qy * bf2f(a[1]) + qz * bf2f(a[2]) + qw * bf2f(a[3]);
        p += __shfl_xor(p, 1);
        p += __shfl_xor(p, 2);
        p += __shfl_xor(p, 4);
        float mnew  = fmaxf(m, p);
        float alpha = __expf(m - mnew);
        float w     = __expf(p - mnew);
        ax = ax * alpha + w * bf2f(a[4]);
        ay = ay * alpha + w * bf2f(a[5]);
        az = az * alpha + w * bf2f(a[6]);
        aw = aw * alpha + w * bf2f(a[7]);
        l = l * alpha + w;
        m = mnew;
    }

    const float inv = (l > 0.f) ? 1.f / l : 0.f;  // deg-0 nodes -> zeros
    ushort4 o;
    o.x = f2bf_rne(ax * inv);
    o.y = f2bf_rne(ay * inv);
    o.z = f2bf_rne(az * inv);
    o.w = f2bf_rne(aw * inv);
    *(ushort4*)(attn + (size_t)node * D_MODEL + 4 * lane) = o;
}

// ---------------- launch ----------------
extern "C" void kernel_launch(void* const* d_in, const int* in_sizes, int n_in,
                              void* d_out, int out_size, void* d_ws, size_t ws_size,
                              hipStream_t stream)
{
    const float* query = (const float*)d_in[0];
    const float* key   = (const float*)d_in[1];
    const float* value = (const float*)d_in[2];
    const int*   edges = (const int*)d_in[3];
    const float* Wq = (const float*)d_in[4];
    const float* bq = (const float*)d_in[5];
    const float* Wk = (const float*)d_in[6];
    const float* bk = (const float*)d_in[7];
    const float* Wv = (const float*)d_in[8];
    const float* bv = (const float*)d_in[9];
    const float* Wo = (const float*)d_in[10];
    const float* bo = (const float*)d_in[11];
    float* out = (float*)d_out;

    const int N = in_sizes[0] / D_MODEL;
    const int E = in_sizes[3] / 2;
    const int* dst = edges;
    const int* src = edges + E;

    char* ws = (char*)d_ws;
    size_t off = 0;
    auto alloc = [&](size_t bytes) {
        void* p = ws + off;
        off += (bytes + 255) & ~(size_t)255;
        return p;
    };
    unsigned short* qbuf  = (unsigned short*)alloc((size_t)N * D_MODEL * 2);
    unsigned short* kvbuf = (unsigned short*)alloc((size_t)N * 2 * D_MODEL * 2); // K|V interleaved
    unsigned short* attnb = (unsigned short*)alloc((size_t)N * D_MODEL * 2);
    unsigned short* Wbuf  = (unsigned short*)alloc((size_t)4 * D_MODEL * D_MODEL * 2);
    int*            counts  = (int*)alloc((size_t)2 * N * 4);   // counts + cursor contiguous
    int*            offsets = (int*)alloc((size_t)(N + 1) * 4);
    int*            ssrc    = (int*)alloc((size_t)E * 4);
    int*            bsums   = (int*)alloc((size_t)256 * 4);

    hipMemsetAsync(counts, 0, (size_t)2 * N * 4, stream);

    const int fused_threads = 4 * 8192 + E;
    conv_weights_hist<<<(fused_threads + 255) / 256, 256, 0, stream>>>(
        Wq, Wk, Wv, Wo, Wbuf, dst, E, counts);

    const int mtiles = (N + 31) / 32;
    gemm_qkv<<<dim3(QBLK, 3), 512, 0, stream>>>(query, key, value, Wbuf,
                                                bq, bk, bv, qbuf, kvbuf, N, mtiles);

    const int G = (N + 256) / 256;  // ceil((N+1)/256)
    block_reduce_kernel<<<G, 256, 0, stream>>>(counts, N, bsums);
    scan_blocks_kernel<<<1, 256, 0, stream>>>(bsums, G);
    scan_write_kernel<<<G, 256, 0, stream>>>(counts, N, bsums, offsets);

    const int eblocks = (E + 255) / 256;
    fill_kernel<<<eblocks, 256, 0, stream>>>(dst, src, E, offsets, counts + N, ssrc);
    attn_kernel<<<(N + 3) / 4, 256, 0, stream>>>(qbuf, kvbuf, offsets, ssrc, attnb, N);

    gemm_out<<<OBLK, 512, 0, stream>>>(attnb, Wbuf + 3 * D_MODEL * D_MODEL, bo, out, N, mtiles);
}